// Round 2
// baseline (368.394 us; speedup 1.0000x reference)
//
#include <hip/hip_runtime.h>
#include <hip/hip_bf16.h>

// messages[e,:] = edge_matrices[type(e)] @ h_w[e,:]
// Inputs (all FLOAT32 per reference): h_v (unused), h_w (E,128),
// edge_features (E,8) one-hot, edge_matrices (8,128,128). Output f32 (E,128).
//
// Strategy: grid (chunk, type). Each block scans 512 edges for its type k
// (expected ~64 matches), builds a match list in LDS, gathers the matched
// h_w rows (f32 -> bf16 convert in-register) into LDS, and computes the
// shared-matrix matvecs via mfma_f32_16x16x32_bf16 (f32 accumulate, f32 out).
// Each of the 4 waves owns a 32-wide h-slice with M_k's B-fragments
// register-resident (converted once). bf16 compute error ~1e-3 << 1.3e-2 thr.

#define NEDGES 320000
#define HIDDEN 128
#define CHUNK  512

typedef __bf16 bf16x8 __attribute__((ext_vector_type(8)));
typedef float  f32x4  __attribute__((ext_vector_type(4)));

__device__ inline bf16x8 pack8(const float4 v0, const float4 v1) {
    bf16x8 p;
    p[0] = (__bf16)v0.x; p[1] = (__bf16)v0.y; p[2] = (__bf16)v0.z; p[3] = (__bf16)v0.w;
    p[4] = (__bf16)v1.x; p[5] = (__bf16)v1.y; p[6] = (__bf16)v1.z; p[7] = (__bf16)v1.w;
    return p;
}

__global__ __launch_bounds__(256, 2) void matrix_message_kernel(
    const float* __restrict__ h_w,   // (E,128) f32
    const float* __restrict__ ef,    // (E,8)   f32 one-hot
    const float* __restrict__ M,     // (8,128,128) f32
    float*       __restrict__ out)   // (E,128) f32
{
    __shared__ unsigned short list[CHUNK];
    __shared__ int cnt;
    __shared__ __align__(16) unsigned char Abuf[64 * 272];  // 64 rows bf16, stride 17*16B

    const int tid  = threadIdx.x;
    const int w    = tid >> 6;       // wave 0..3 -> h-slice [32w, 32w+32)
    const int lane = tid & 63;
    const int q    = lane >> 4;      // quad 0..3
    const int c    = lane & 15;
    const int k    = blockIdx.y;     // edge type
    const int e0   = blockIdx.x * CHUNK;

    if (tid == 0) cnt = 0;

    // B fragments, register-resident (converted f32->bf16 once per block).
    // D[m][n] = sum_k A[m][k]*B[k][n]; m=edge, n=h (within slice), k=d.
    // B[k=q*8+j][n=c] = M_k[h = 32w + nt*16 + c][d = kk*32 + q*8 + j]
    const float* Mb = M + (size_t)k * (HIDDEN * HIDDEN);
    bf16x8 b[2][4];
#pragma unroll
    for (int nt = 0; nt < 2; ++nt)
#pragma unroll
        for (int kk = 0; kk < 4; ++kk) {
            const int h = 32 * w + nt * 16 + c;
            const float4* s4 = (const float4*)(Mb + (size_t)h * HIDDEN + kk * 32 + q * 8);
            b[nt][kk] = pack8(s4[0], s4[1]);
        }

    __syncthreads();  // cnt = 0 visible before atomics

    // Scan this chunk's one-hot column k; append matches to LDS list.
#pragma unroll
    for (int t = tid; t < CHUNK; t += 256) {
        float f = ef[(size_t)(e0 + t) * 8 + k];
        if (f > 0.5f) {
            int p = atomicAdd(&cnt, 1);
            list[p] = (unsigned short)t;
        }
    }
    __syncthreads();

    const int n_g = cnt;
    for (int g = 0; g < n_g; g += 64) {
        // Gather up to 64 matched h_w rows (f32, 512 B each) into LDS as bf16.
        // 16 lanes per row, each lane: 2x float4 load -> bf16x8 -> 16 B LDS.
#pragma unroll
        for (int r4 = 0; r4 < 4; ++r4) {
            const int r   = r4 * 16 + (tid >> 4);
            const int idx = g + r;
            const int e_loc = list[(idx < n_g) ? idx : 0];
            const float4* src = (const float4*)(h_w + (size_t)(e0 + e_loc) * HIDDEN);
            float4 v0 = src[(tid & 15) * 2];
            float4 v1 = src[(tid & 15) * 2 + 1];
            *(bf16x8*)(Abuf + r * 272 + (tid & 15) * 16) = pack8(v0, v1);
        }
        __syncthreads();

        // 4 m-subtiles of 16 edges; skip fully-padded subtiles (uniform cond).
        for (int s = 0; s < 4 && g + s * 16 < n_g; ++s) {
            bf16x8 a[4];  // A[m=lane&15][d = kk*32 + q*8 + j]
#pragma unroll
            for (int kk = 0; kk < 4; ++kk)
                a[kk] = *(const bf16x8*)(Abuf + (s * 16 + c) * 272 + kk * 64 + q * 16);

            f32x4 acc0 = {0.f, 0.f, 0.f, 0.f};
            f32x4 acc1 = {0.f, 0.f, 0.f, 0.f};
#pragma unroll
            for (int kk = 0; kk < 4; ++kk) {
                acc0 = __builtin_amdgcn_mfma_f32_16x16x32_bf16(a[kk], b[0][kk], acc0, 0, 0, 0);
                acc1 = __builtin_amdgcn_mfma_f32_16x16x32_bf16(a[kk], b[1][kk], acc1, 0, 0, 0);
            }

            // C/D: col = lane&15 (h within 16), row = q*4 + reg (edge in subtile)
#pragma unroll
            for (int reg = 0; reg < 4; ++reg) {
                const int idx = g + s * 16 + q * 4 + reg;
                if (idx < n_g) {
                    const size_t row = (size_t)(e0 + list[idx]) * HIDDEN;
                    out[row + 32 * w + c]      = acc0[reg];
                    out[row + 32 * w + 16 + c] = acc1[reg];
                }
            }
        }
        __syncthreads();  // Abuf reused next group
    }
}

extern "C" void kernel_launch(void* const* d_in, const int* in_sizes, int n_in,
                              void* d_out, int out_size, void* d_ws, size_t ws_size,
                              hipStream_t stream) {
    // d_in order: h_v (unused), h_w, edge_features, edge_matrices — all f32
    const float* h_w = (const float*)d_in[1];
    const float* ef  = (const float*)d_in[2];
    const float* M   = (const float*)d_in[3];
    float*       out = (float*)d_out;

    dim3 grid(NEDGES / CHUNK, 8, 1);   // 625 chunks x 8 types
    dim3 block(256, 1, 1);
    matrix_message_kernel<<<grid, block, 0, stream>>>(h_w, ef, M, out);
}